// Round 22
// baseline (209.369 us; speedup 1.0000x reference)
//
#include <hip/hip_runtime.h>
#include <cmath>

#define B_   16
#define C_   256
#define HW_  64
#define N_   4096          // 64*64
#define NH_  8
#define HD_  32
#define M_   (B_ * N_)     // 65536
#define QKVC (3 * C_)      // 768
#define EPS_ 1e-6f

typedef short bf16x8 __attribute__((ext_vector_type(8)));
typedef float f32x4 __attribute__((ext_vector_type(4)));
typedef unsigned int u32x4 __attribute__((ext_vector_type(4)));

__device__ __forceinline__ float b2f(unsigned short u) {
  union { unsigned int i; float f; } v;
  v.i = ((unsigned int)u) << 16;
  return v.f;
}
// bf16 pair extraction from a packed uint (pure register ops)
__device__ __forceinline__ float blo(unsigned int u) {
  union { unsigned int i; float f; } v; v.i = u << 16; return v.f;
}
__device__ __forceinline__ float bhi(unsigned int u) {
  union { unsigned int i; float f; } v; v.i = u & 0xffff0000u; return v.f;
}
__device__ __forceinline__ unsigned short f2b(float f) {
  union { float f; unsigned int i; } v;
  v.f = f;
  unsigned int r = v.i + 0x7FFFu + ((v.i >> 16) & 1u);  // RNE
  return (unsigned short)(r >> 16);
}
__device__ __forceinline__ void gload_lds16(const void* g, void* l) {
  __builtin_amdgcn_global_load_lds(
      (const __attribute__((address_space(1))) void*)g,
      (__attribute__((address_space(3))) void*)l, 16, 0, 0);
}

// ---------------------------------------------------------------------------
// K0a: transpose-cast x [b][c][n] f32 -> xT [b][n][c] bf16
// ---------------------------------------------------------------------------
__global__ __launch_bounds__(256) void k_cast_x(const float* __restrict__ x,
                                                unsigned short* __restrict__ xT) {
  __shared__ float t[32][33];
  const int n0 = blockIdx.x * 32, c0 = blockIdx.y * 32, b = blockIdx.z;
  const int tid = threadIdx.x;
  const int r = tid >> 3, g = (tid & 7) * 4;
  float4 v = *reinterpret_cast<const float4*>(
      &x[((size_t)(b * C_ + c0 + r)) * N_ + n0 + g]);
  t[r][g + 0] = v.x; t[r][g + 1] = v.y; t[r][g + 2] = v.z; t[r][g + 3] = v.w;
  __syncthreads();
  ushort4 o;
  o.x = f2b(t[g + 0][r]); o.y = f2b(t[g + 1][r]);
  o.z = f2b(t[g + 2][r]); o.w = f2b(t[g + 3][r]);
  *reinterpret_cast<ushort4*>(&xT[((size_t)(b * N_ + n0 + r)) * C_ + c0 + g]) = o;
}

// ---------------------------------------------------------------------------
// K0b: cast qkv_w (768x256) and proj_w (256x256) to bf16 (contiguous dst)
// ---------------------------------------------------------------------------
__global__ __launch_bounds__(256) void k_cast_w(const float* __restrict__ w1,
                                                const float* __restrict__ w2,
                                                unsigned short* __restrict__ dst) {
  const int g4 = (blockIdx.x * 256 + threadIdx.x) * 4;  // < 262144
  float4 v;
  if (g4 < 196608) v = *reinterpret_cast<const float4*>(w1 + g4);
  else             v = *reinterpret_cast<const float4*>(w2 + (g4 - 196608));
  ushort4 o;
  o.x = f2b(v.x); o.y = f2b(v.y); o.z = f2b(v.z); o.w = f2b(v.w);
  *reinterpret_cast<ushort4*>(dst + g4) = o;
}

// ---------------------------------------------------------------------------
// K0c: rsc[c] = 1/softplus(scale[c]) — computed ONCE.
// ---------------------------------------------------------------------------
__global__ void k_prep_scale(const float* __restrict__ scale,
                             float* __restrict__ rsc) {
  const int c = threadIdx.x;
  rsc[c] = 1.f / log1pf(expf(scale[c]));
}

// ---------------------------------------------------------------------------
// K1/K6: bf16 MFMA GEMM, 128x128 tile, BK=64, 4 waves (2x2 of 64x64).
// Row-major in-band XCD ordering (r14). Cached stores both modes (r18 A/B).
// ---------------------------------------------------------------------------
template <int LDA, int OUTMODE, int NCOL>
__global__ __launch_bounds__(256) void k_gemm(
    const unsigned short* __restrict__ A, const unsigned short* __restrict__ W,
    const float* __restrict__ bias, void* __restrict__ outp) {
  __shared__ unsigned short As[128 * 64];
  __shared__ unsigned short Bs[128 * 64];
  const int tid = threadIdx.x;
  const int wid = tid >> 6, lane = tid & 63;
  const int lin = blockIdx.x + blockIdx.y * 512;
  const int bandp = lin >> 3;
  const int rowb = bandp / NCOL;
  const int colb = bandp - rowb * NCOL;
  const int m0 = (((lin & 7) << 6) + rowb) * 128;
  const int col0 = colb * 128;
  const int wr = wid >> 1, wc = wid & 1;

  const int lrow = lane >> 3;
  const int sl = (lane & 7) ^ (lrow & 7);  // logical 16B-slot this lane fetches

  f32x4 acc[4][4];
#pragma unroll
  for (int i = 0; i < 4; ++i)
#pragma unroll
    for (int j = 0; j < 4; ++j) acc[i][j] = (f32x4){0.f, 0.f, 0.f, 0.f};

  for (int kt = 0; kt < 4; ++kt) {
    const int k0 = kt * 64;
#pragma unroll
    for (int q = 0; q < 4; ++q) {
      const int chunk = wid * 4 + q;          // 0..15, 8 rows each
      const int row = chunk * 8 + lrow;       // 0..127
      gload_lds16(A + (size_t)(m0 + row) * LDA + k0 + sl * 8, &As[chunk * 512]);
      gload_lds16(W + (size_t)(col0 + row) * 256 + k0 + sl * 8, &Bs[chunk * 512]);
    }
    __syncthreads();  // drains vmcnt -> staged tiles visible

    bf16x8 fa[2][4], fb[2][4];
#pragma unroll
    for (int i = 0; i < 4; ++i) {
      const int ra = wr * 64 + i * 16 + (lane & 15);
      const int rb = wc * 64 + i * 16 + (lane & 15);
#pragma unroll
      for (int ks = 0; ks < 2; ++ks) {
        const int s = ks * 4 + (lane >> 4);
        fa[ks][i] = *reinterpret_cast<const bf16x8*>(
            &As[ra * 64 + ((s ^ (ra & 7)) * 8)]);
        fb[ks][i] = *reinterpret_cast<const bf16x8*>(
            &Bs[rb * 64 + ((s ^ (rb & 7)) * 8)]);
      }
    }
#pragma unroll
    for (int i = 0; i < 4; ++i)
#pragma unroll
      for (int j = 0; j < 4; ++j) {
        acc[i][j] = __builtin_amdgcn_mfma_f32_16x16x32_bf16(fa[0][i], fb[0][j],
                                                            acc[i][j], 0, 0, 0);
        acc[i][j] = __builtin_amdgcn_mfma_f32_16x16x32_bf16(fa[1][i], fb[1][j],
                                                            acc[i][j], 0, 0, 0);
      }
    __syncthreads();
  }

  // C/D layout: col = lane&15, row = (lane>>4)*4 + reg   [m89/m91]
  if (OUTMODE == 0) {
    unsigned short* O = (unsigned short*)outp;
#pragma unroll
    for (int j = 0; j < 4; ++j) {
      const int colg = col0 + wc * 64 + j * 16 + (lane & 15);
      const float bb = bias[colg];
#pragma unroll
      for (int i = 0; i < 4; ++i) {
        const int mrow = m0 + wr * 64 + i * 16 + ((lane >> 4) << 2);
#pragma unroll
        for (int r = 0; r < 4; ++r)
          O[(size_t)(mrow + r) * QKVC + colg] = f2b(acc[i][j][r] + bb);
      }
    }
  } else {
    float* O = (float*)outp;
    const int b = m0 >> 12;
    const int nb0 = (m0 & 4095) + wr * 64;
#pragma unroll
    for (int j = 0; j < 4; ++j) {
      const int colg = col0 + wc * 64 + j * 16 + (lane & 15);
      const float bb = bias[colg];
#pragma unroll
      for (int i = 0; i < 4; ++i) {
        const int nb = nb0 + i * 16 + ((lane >> 4) << 2);
        f32x4 o = acc[i][j];
        o += bb;
        *reinterpret_cast<f32x4*>(&O[((size_t)(b * C_ + colg)) * N_ + nb]) = o;
      }
    }
  }
}

// ---------------------------------------------------------------------------
// K2+K3 FUSED (ROUND-22): focus + k^T v accumulation in one kernel.
// Rationale: focused k is consumed ONLY by the kv outer product — it never
// needs to hit HBM; and kv_part's k,v re-read (67 MB) duplicates what focus
// had in registers. Fused traffic: read qkv rows once (100.7 MB), write only
// focused q (33.5 MB), kvp partials 16.8 MB. Was ~210 MB across two kernels.
// Block = (chunk of 128 tokens, b); 512 blocks. Per 16-token stage: 4 waves
// focus 4 tokens each (wave-per-token, same math as before; k kept in f32 —
// one FEWER bf16 rounding than the old k path), staged to LDS f32; then all
// 256 threads accumulate: thread owns (h = tid>>5, c = tid&31), acc8[8] f32x4
// over d. ksf read is stride-1 (conflict-free); vsf read is 2 broadcast
// addresses per wave. 16 barriers/block with ~700 inst between.
// ---------------------------------------------------------------------------
#define KVP_CHUNKS 32
__global__ __launch_bounds__(256) void k_focus_kv(
    unsigned short* __restrict__ qkv, const float* __restrict__ rsc,
    float* __restrict__ kvp, float* __restrict__ ksp) {
  const int chunk = blockIdx.x;   // 0..31
  const int b = blockIdx.y;       // 0..15
  const int tid = threadIdx.x;
  const int wave = tid >> 6, lane = tid & 63;
  __shared__ float ksf[16][256];  // 16 KB: focused k (f32), 16 tokens
  __shared__ float vsf[16][256];  // 16 KB: v (f32)

  const f32x4 rs = *reinterpret_cast<const f32x4*>(rsc + lane * 4);
  f32x4 acc8[8];
#pragma unroll
  for (int i = 0; i < 8; ++i) acc8[i] = (f32x4){0.f, 0.f, 0.f, 0.f};
  float ksum = 0.f;
  const int h = tid >> 5, c = tid & 31;
  const int j0 = chunk * 128;

  for (int stage = 0; stage < 8; ++stage) {
    // ---- focus phase: wave processes tokens srow = wave*4 + s
#pragma unroll
    for (int s = 0; s < 4; ++s) {
      const int srow = wave * 4 + s;
      const size_t base =
          ((size_t)(b * N_ + j0 + stage * 16 + srow)) * QKVC + lane * 4;
      const uint2 qu = *reinterpret_cast<const uint2*>(qkv + base);
      const uint2 ku = *reinterpret_cast<const uint2*>(qkv + base + C_);
      const uint2 vu = *reinterpret_cast<const uint2*>(qkv + base + 2 * C_);

      float q[4], k[4], q3[4], k3[4];
      q[0] = blo(qu.x); q[1] = bhi(qu.x); q[2] = blo(qu.y); q[3] = bhi(qu.y);
      k[0] = blo(ku.x); k[1] = bhi(ku.x); k[2] = blo(ku.y); k[3] = bhi(ku.y);

      float sq2 = 0.f, sq6 = 0.f, sk2 = 0.f, sk6 = 0.f;
#pragma unroll
      for (int i = 0; i < 4; ++i) {
        q[i] = (fmaxf(q[i], 0.f) + EPS_) * rs[i];
        k[i] = (fmaxf(k[i], 0.f) + EPS_) * rs[i];
        const float q2 = q[i] * q[i], k2 = k[i] * k[i];
        q3[i] = q2 * q[i];
        k3[i] = k2 * k[i];
        sq2 += q2; sk2 += k2;
        sq6 += q3[i] * q3[i];
        sk6 += k3[i] * k3[i];
      }
#pragma unroll
      for (int off = 1; off < 64; off <<= 1) {
        sq2 += __shfl_xor(sq2, off);
        sq6 += __shfl_xor(sq6, off);
        sk2 += __shfl_xor(sk2, off);
        sk6 += __shfl_xor(sk6, off);
      }
      const float fq = sqrtf(sq2 / sq6);
      const float fk = sqrtf(sk2 / sk6);

      // write focused q back (bf16); k stays on-chip in f32
      uint2 oq;
      oq.x = (unsigned int)f2b(q3[0] * fq) |
             ((unsigned int)f2b(q3[1] * fq) << 16);
      oq.y = (unsigned int)f2b(q3[2] * fq) |
             ((unsigned int)f2b(q3[3] * fq) << 16);
      *reinterpret_cast<uint2*>(qkv + base) = oq;

      const f32x4 kf = {k3[0] * fk, k3[1] * fk, k3[2] * fk, k3[3] * fk};
      const f32x4 vf = {blo(vu.x), bhi(vu.x), blo(vu.y), bhi(vu.y)};
      *reinterpret_cast<f32x4*>(&ksf[srow][lane * 4]) = kf;
      *reinterpret_cast<f32x4*>(&vsf[srow][lane * 4]) = vf;
    }
    __syncthreads();
    // ---- accumulate phase: thread = (h, c); 16 tokens
#pragma unroll 4
    for (int tt = 0; tt < 16; ++tt) {
      const float kc = ksf[tt][tid];
      ksum += kc;
      const float* vrow = &vsf[tt][h * 32];
#pragma unroll
      for (int d4 = 0; d4 < 8; ++d4) {
        const f32x4 vv = *reinterpret_cast<const f32x4*>(&vrow[d4 * 4]);
        acc8[d4] += kc * vv;
      }
    }
    __syncthreads();  // staging buffers free for next stage
  }

  float* kvo = kvp + ((size_t)chunk * 128 + b * 8 + h) * 1024 + c * 32;
#pragma unroll
  for (int d4 = 0; d4 < 8; ++d4)
    *reinterpret_cast<f32x4*>(&kvo[d4 * 4]) = acc8[d4];
  ksp[((size_t)chunk * 128 + b * 8 + h) * 32 + c] = ksum;
}

// ---------------------------------------------------------------------------
// K3b: reduce 32 chunks ONCE -> kvb[128][1024], ksumb[128][32].
// ---------------------------------------------------------------------------
__global__ __launch_bounds__(256) void k_kv_reduce(
    const float* __restrict__ kvp, const float* __restrict__ ksp,
    float* __restrict__ kv, float* __restrict__ ksum) {
  const int bh = blockIdx.x;
  for (int p = threadIdx.x; p < 1024; p += 256) {
    float s = 0.f;
#pragma unroll
    for (int ch = 0; ch < KVP_CHUNKS; ++ch)
      s += kvp[((size_t)ch * 128 + bh) * 1024 + p];
    kv[bh * 1024 + p] = s;
  }
  if (threadIdx.x < 32) {
    float s = 0.f;
#pragma unroll
    for (int ch = 0; ch < KVP_CHUNKS; ++ch)
      s += ksp[((size_t)ch * 128 + bh) * 32 + threadIdx.x];
    ksum[bh * 32 + threadIdx.x] = s;
  }
}

// ---------------------------------------------------------------------------
// K4: fused attention MFMA + depthwise conv (r21 structure: R=4, no kv_s LDS,
// B-frags direct from L2-hot kvb, v-halo gloads fly under the MFMA phase).
// ---------------------------------------------------------------------------
__global__ __launch_bounds__(256) void k_attn_conv_f(
    unsigned short* __restrict__ qkv, const float* __restrict__ kv,
    const float* __restrict__ ksum, const float* __restrict__ dwc_w,
    const float* __restrict__ dwc_b) {
  const int lin = blockIdx.x;               // 0..2047
  const int g2 = (lin & 7) * 256 + (lin >> 3);
  const int bh = g2 >> 4;                   // 0..127
  const int ig = g2 & 15;                   // 4-row group
  const int i0 = ig * 4;
  const int b = bh >> 3, h = bh & 7;
  const int tid = threadIdx.x;
  const int wave = tid >> 6, lane = tid & 63;

  __shared__ float w_s[800];                // [tap][ch]
  __shared__ float b_s[32];
  __shared__ unsigned short v_s[8 * 64 * 32];  // [halo-row][col][ch] 32 KB

  // ---- issue v-halo gloads FIRST; they fly under the attn MFMA phase
#pragma unroll
  for (int rr = 0; rr < 8; ++rr) {
    const int ii = i0 + rr - 2;             // block-uniform condition
    if (ii < 0 || ii >= 64) continue;
    gload_lds16(qkv + ((size_t)(b * N_ + ii * 64 + wave * 16 + (lane >> 2))) * QKVC +
                    2 * C_ + h * HD_ + (lane & 3) * 8,
                &v_s[rr * 2048 + wave * 512]);
  }
  // conv weights into LDS (read only after the mid-kernel barrier)
  for (int p = tid; p < 800; p += 256)
    w_s[p] = dwc_w[(p & 31) * 25 + (p >> 5)];
  if (tid < 32) b_s[tid] = dwc_b[tid];

  // ---- attn phase: wave handles image row i0+wave (64 tokens).
  {
    const int kb = (lane >> 4) * 8;
    const int col = lane & 15;
    const float* kvb_row = kv + bh * 1024;
    const float* ksb = ksum + bh * 32;
    bf16x8 bh0, bh1, bl0, bl1;
    float ks0[8];
#pragma unroll
    for (int t = 0; t < 8; ++t) {
      const float v0 = kvb_row[(kb + t) * 32 + col];
      const float v1 = kvb_row[(kb + t) * 32 + col + 16];
      const unsigned short h0 = f2b(v0), h1 = f2b(v1);
      ((unsigned short*)&bh0)[t] = h0;
      ((unsigned short*)&bh1)[t] = h1;
      ((unsigned short*)&bl0)[t] = f2b(v0 - b2f(h0));
      ((unsigned short*)&bl1)[t] = f2b(v1 - b2f(h1));
      ks0[t] = ksb[kb + t];
    }
    const int r0 = (i0 + wave) * 64;
#pragma unroll
    for (int rt = 0; rt < 4; ++rt) {
      const int row = r0 + rt * 16 + (lane & 15);
      const bf16x8 a = *reinterpret_cast<const bf16x8*>(
          qkv + (size_t)(b * N_ + row) * QKVC + h * HD_ + kb);
      float zp = 0.f;
#pragma unroll
      for (int t = 0; t < 8; ++t)
        zp += b2f(((const unsigned short*)&a)[t]) * ks0[t];
      zp += __shfl_xor(zp, 16);
      zp += __shfl_xor(zp, 32);
      const float z = 1.f / (zp + EPS_);

      f32x4 acc0 = {0.f, 0.f, 0.f, 0.f}, acc1 = {0.f, 0.f, 0.f, 0.f};
      acc0 = __builtin_amdgcn_mfma_f32_16x16x32_bf16(a, bl0, acc0, 0, 0, 0);
      acc1 = __builtin_amdgcn_mfma_f32_16x16x32_bf16(a, bl1, acc1, 0, 0, 0);
      acc0 = __builtin_amdgcn_mfma_f32_16x16x32_bf16(a, bh0, acc0, 0, 0, 0);
      acc1 = __builtin_amdgcn_mfma_f32_16x16x32_bf16(a, bh1, acc1, 0, 0, 0);

#pragma unroll
      for (int r = 0; r < 4; ++r) {
        const int rr = (lane >> 4) * 4 + r;
        const float zr = __shfl(z, rr);
        unsigned short* op =
            qkv + (size_t)(b * N_ + r0 + rt * 16 + rr) * QKVC + h * HD_;
        op[col] = f2b(acc0[r] * zr);
        op[col + 16] = f2b(acc1[r] * zr);
      }
    }
  }
  __syncthreads();  // drains v-halo gloads AND attn q-slot writes (block-local)

  // ---- conv phase: thread = (image col j, channel group); halo-row reuse
  {
    const int j = tid >> 2;
    const int d0 = (tid & 3) * 8;
    float fm[4][8];
#pragma unroll
    for (int r = 0; r < 4; ++r)
#pragma unroll
      for (int dd = 0; dd < 8; ++dd) fm[r][dd] = b_s[d0 + dd];

#pragma unroll
    for (int lr = 0; lr < 8; ++lr) {        // halo row (image row i0+lr-2)
      const int ii = i0 + lr - 2;
      if (ii < 0 || ii >= 64) continue;     // block-uniform
#pragma unroll
      for (int kj = 0; kj < 5; ++kj) {
        const int jj = j + kj - 2;
        if (jj < 0 || jj >= 64) continue;
        const unsigned int* vr = reinterpret_cast<const unsigned int*>(
            &v_s[lr * 2048 + jj * 32 + d0]);
        float vf[8];
#pragma unroll
        for (int p = 0; p < 4; ++p) {       // unpack ONCE per loaded value
          const unsigned int vu = vr[p];
          vf[2 * p + 0] = blo(vu);
          vf[2 * p + 1] = bhi(vu);
        }
#pragma unroll
        for (int r = 0; r < 4; ++r) {       // all output rows this row feeds
          const int kr = lr - r;            // compile-time after unroll
          if (kr < 0 || kr > 4) continue;
          const float* wt = &w_s[(kr * 5 + kj) * 32 + d0];
#pragma unroll
          for (int dd = 0; dd < 8; ++dd) fm[r][dd] += vf[dd] * wt[dd];
        }
      }
    }

#pragma unroll
    for (int r = 0; r < 4; ++r) {
      const int i = i0 + r;
      unsigned int* orow = reinterpret_cast<unsigned int*>(
          qkv + ((size_t)(b * N_ + i * 64 + j)) * QKVC + h * HD_ + d0);
      uint4 cur = *reinterpret_cast<const uint4*>(orow);
      unsigned int o[4] = {cur.x, cur.y, cur.z, cur.w};
#pragma unroll
      for (int p = 0; p < 4; ++p) {
        const unsigned int lo = f2b(blo(o[p]) + fm[r][2 * p + 0]);
        const unsigned int hi = f2b(bhi(o[p]) + fm[r][2 * p + 1]);
        o[p] = lo | (hi << 16);
      }
      *reinterpret_cast<uint4*>(orow) = make_uint4(o[0], o[1], o[2], o[3]);
    }
  }
}

// ---------------------------------------------------------------------------
extern "C" void kernel_launch(void* const* d_in, const int* in_sizes, int n_in,
                              void* d_out, int out_size, void* d_ws,
                              size_t ws_size, hipStream_t stream) {
  (void)in_sizes; (void)n_in; (void)out_size; (void)ws_size;
  const float* x      = (const float*)d_in[0];
  const float* qkv_w  = (const float*)d_in[1];
  const float* qkv_b  = (const float*)d_in[2];
  const float* proj_w = (const float*)d_in[3];
  const float* proj_b = (const float*)d_in[4];
  const float* dwc_w  = (const float*)d_in[5];
  const float* dwc_b  = (const float*)d_in[6];
  const float* scale  = (const float*)d_in[7];
  float* out = (float*)d_out;

  char* w = (char*)d_ws;
  unsigned short* xT   = (unsigned short*)w; w += (size_t)M_ * C_ * 2;     // 33.6MB
  unsigned short* qkvb = (unsigned short*)w; w += (size_t)M_ * QKVC * 2;   // 100.7MB
  // Reserve space for BOTH weight matrices (round-3 NaN was wp aliasing kvp).
  unsigned short* wq   = (unsigned short*)w; w += (size_t)(QKVC + C_) * C_ * 2;
  unsigned short* wp   = wq + (size_t)QKVC * C_;
  float* kvp   = (float*)w;                  w += (size_t)KVP_CHUNKS * 128 * 1024 * 4;
  float* ksp   = (float*)w;                  w += (size_t)KVP_CHUNKS * 128 * 32 * 4;
  float* kvb   = (float*)w;                  w += 128 * 1024 * 4;
  float* ksumb = (float*)w;                  w += 128 * 32 * 4;
  float* rscb  = (float*)w;                  w += 256 * 4;

  k_prep_scale<<<1, 256, 0, stream>>>(scale, rscb);
  k_cast_x<<<dim3(N_ / 32, C_ / 32, B_), 256, 0, stream>>>(x, xT);
  k_cast_w<<<256, 256, 0, stream>>>(qkv_w, proj_w, wq);
  k_gemm<256, 0, 6><<<dim3(512, 6), 256, 0, stream>>>(
      xT, wq, qkv_b, (void*)qkvb);
  k_focus_kv<<<dim3(KVP_CHUNKS, B_), 256, 0, stream>>>(qkvb, rscb, kvp, ksp);
  k_kv_reduce<<<128, 256, 0, stream>>>(kvp, ksp, kvb, ksumb);
  k_attn_conv_f<<<2048, 256, 0, stream>>>(qkvb, kvb, ksumb, dwc_w, dwc_b);
  k_gemm<768, 1, 2><<<dim3(512, 2), 256, 0, stream>>>(
      qkvb, wp, proj_b, (void*)out);
}

// Round 23
// 194.356 us; speedup vs baseline: 1.0772x; 1.0772x over previous
//
#include <hip/hip_runtime.h>
#include <cmath>

#define B_   16
#define C_   256
#define HW_  64
#define N_   4096          // 64*64
#define NH_  8
#define HD_  32
#define M_   (B_ * N_)     // 65536
#define QKVC (3 * C_)      // 768
#define EPS_ 1e-6f

typedef short bf16x8 __attribute__((ext_vector_type(8)));
typedef float f32x4 __attribute__((ext_vector_type(4)));
typedef unsigned int u32x4 __attribute__((ext_vector_type(4)));

__device__ __forceinline__ float b2f(unsigned short u) {
  union { unsigned int i; float f; } v;
  v.i = ((unsigned int)u) << 16;
  return v.f;
}
__device__ __forceinline__ float blo(unsigned int u) {
  union { unsigned int i; float f; } v; v.i = u << 16; return v.f;
}
__device__ __forceinline__ float bhi(unsigned int u) {
  union { unsigned int i; float f; } v; v.i = u & 0xffff0000u; return v.f;
}
__device__ __forceinline__ unsigned short f2b(float f) {
  union { float f; unsigned int i; } v;
  v.f = f;
  unsigned int r = v.i + 0x7FFFu + ((v.i >> 16) & 1u);  // RNE
  return (unsigned short)(r >> 16);
}
__device__ __forceinline__ void gload_lds16(const void* g, void* l) {
  __builtin_amdgcn_global_load_lds(
      (const __attribute__((address_space(1))) void*)g,
      (__attribute__((address_space(3))) void*)l, 16, 0, 0);
}

// ---------------------------------------------------------------------------
// K0a: transpose-cast x [b][c][n] f32 -> xT [b][n][c] bf16
// ---------------------------------------------------------------------------
__global__ __launch_bounds__(256) void k_cast_x(const float* __restrict__ x,
                                                unsigned short* __restrict__ xT) {
  __shared__ float t[32][33];
  const int n0 = blockIdx.x * 32, c0 = blockIdx.y * 32, b = blockIdx.z;
  const int tid = threadIdx.x;
  const int r = tid >> 3, g = (tid & 7) * 4;
  float4 v = *reinterpret_cast<const float4*>(
      &x[((size_t)(b * C_ + c0 + r)) * N_ + n0 + g]);
  t[r][g + 0] = v.x; t[r][g + 1] = v.y; t[r][g + 2] = v.z; t[r][g + 3] = v.w;
  __syncthreads();
  ushort4 o;
  o.x = f2b(t[g + 0][r]); o.y = f2b(t[g + 1][r]);
  o.z = f2b(t[g + 2][r]); o.w = f2b(t[g + 3][r]);
  *reinterpret_cast<ushort4*>(&xT[((size_t)(b * N_ + n0 + r)) * C_ + c0 + g]) = o;
}

// ---------------------------------------------------------------------------
// K0b: cast qkv_w (768x256) and proj_w (256x256) to bf16 (contiguous dst)
// ---------------------------------------------------------------------------
__global__ __launch_bounds__(256) void k_cast_w(const float* __restrict__ w1,
                                                const float* __restrict__ w2,
                                                unsigned short* __restrict__ dst) {
  const int g4 = (blockIdx.x * 256 + threadIdx.x) * 4;  // < 262144
  float4 v;
  if (g4 < 196608) v = *reinterpret_cast<const float4*>(w1 + g4);
  else             v = *reinterpret_cast<const float4*>(w2 + (g4 - 196608));
  ushort4 o;
  o.x = f2b(v.x); o.y = f2b(v.y); o.z = f2b(v.z); o.w = f2b(v.w);
  *reinterpret_cast<ushort4*>(dst + g4) = o;
}

// ---------------------------------------------------------------------------
// K0c: rsc[c] = 1/softplus(scale[c]) — computed ONCE.
// ---------------------------------------------------------------------------
__global__ void k_prep_scale(const float* __restrict__ scale,
                             float* __restrict__ rsc) {
  const int c = threadIdx.x;
  rsc[c] = 1.f / log1pf(expf(scale[c]));
}

// ---------------------------------------------------------------------------
// K1/K6: bf16 MFMA GEMM, 128x128 tile, BK=64, 4 waves (2x2 of 64x64).
// Row-major in-band XCD ordering (r14). Cached stores both modes (r18 A/B).
// ---------------------------------------------------------------------------
template <int LDA, int OUTMODE, int NCOL>
__global__ __launch_bounds__(256) void k_gemm(
    const unsigned short* __restrict__ A, const unsigned short* __restrict__ W,
    const float* __restrict__ bias, void* __restrict__ outp) {
  __shared__ unsigned short As[128 * 64];
  __shared__ unsigned short Bs[128 * 64];
  const int tid = threadIdx.x;
  const int wid = tid >> 6, lane = tid & 63;
  const int lin = blockIdx.x + blockIdx.y * 512;
  const int bandp = lin >> 3;
  const int rowb = bandp / NCOL;
  const int colb = bandp - rowb * NCOL;
  const int m0 = (((lin & 7) << 6) + rowb) * 128;
  const int col0 = colb * 128;
  const int wr = wid >> 1, wc = wid & 1;

  const int lrow = lane >> 3;
  const int sl = (lane & 7) ^ (lrow & 7);  // logical 16B-slot this lane fetches

  f32x4 acc[4][4];
#pragma unroll
  for (int i = 0; i < 4; ++i)
#pragma unroll
    for (int j = 0; j < 4; ++j) acc[i][j] = (f32x4){0.f, 0.f, 0.f, 0.f};

  for (int kt = 0; kt < 4; ++kt) {
    const int k0 = kt * 64;
#pragma unroll
    for (int q = 0; q < 4; ++q) {
      const int chunk = wid * 4 + q;          // 0..15, 8 rows each
      const int row = chunk * 8 + lrow;       // 0..127
      gload_lds16(A + (size_t)(m0 + row) * LDA + k0 + sl * 8, &As[chunk * 512]);
      gload_lds16(W + (size_t)(col0 + row) * 256 + k0 + sl * 8, &Bs[chunk * 512]);
    }
    __syncthreads();  // drains vmcnt -> staged tiles visible

    bf16x8 fa[2][4], fb[2][4];
#pragma unroll
    for (int i = 0; i < 4; ++i) {
      const int ra = wr * 64 + i * 16 + (lane & 15);
      const int rb = wc * 64 + i * 16 + (lane & 15);
#pragma unroll
      for (int ks = 0; ks < 2; ++ks) {
        const int s = ks * 4 + (lane >> 4);
        fa[ks][i] = *reinterpret_cast<const bf16x8*>(
            &As[ra * 64 + ((s ^ (ra & 7)) * 8)]);
        fb[ks][i] = *reinterpret_cast<const bf16x8*>(
            &Bs[rb * 64 + ((s ^ (rb & 7)) * 8)]);
      }
    }
#pragma unroll
    for (int i = 0; i < 4; ++i)
#pragma unroll
      for (int j = 0; j < 4; ++j) {
        acc[i][j] = __builtin_amdgcn_mfma_f32_16x16x32_bf16(fa[0][i], fb[0][j],
                                                            acc[i][j], 0, 0, 0);
        acc[i][j] = __builtin_amdgcn_mfma_f32_16x16x32_bf16(fa[1][i], fb[1][j],
                                                            acc[i][j], 0, 0, 0);
      }
    __syncthreads();
  }

  // C/D layout: col = lane&15, row = (lane>>4)*4 + reg   [m89/m91]
  if (OUTMODE == 0) {
    unsigned short* O = (unsigned short*)outp;
#pragma unroll
    for (int j = 0; j < 4; ++j) {
      const int colg = col0 + wc * 64 + j * 16 + (lane & 15);
      const float bb = bias[colg];
#pragma unroll
      for (int i = 0; i < 4; ++i) {
        const int mrow = m0 + wr * 64 + i * 16 + ((lane >> 4) << 2);
#pragma unroll
        for (int r = 0; r < 4; ++r)
          O[(size_t)(mrow + r) * QKVC + colg] = f2b(acc[i][j][r] + bb);
      }
    }
  } else {
    float* O = (float*)outp;
    const int b = m0 >> 12;
    const int nb0 = (m0 & 4095) + wr * 64;
#pragma unroll
    for (int j = 0; j < 4; ++j) {
      const int colg = col0 + wc * 64 + j * 16 + (lane & 15);
      const float bb = bias[colg];
#pragma unroll
      for (int i = 0; i < 4; ++i) {
        const int nb = nb0 + i * 16 + ((lane >> 4) << 2);
        f32x4 o = acc[i][j];
        o += bb;
        *reinterpret_cast<f32x4*>(&O[((size_t)(b * C_ + colg)) * N_ + nb]) = o;
      }
    }
  }
}

// ---------------------------------------------------------------------------
// K2: focusing feature map, wave-per-token (round 9).
// ---------------------------------------------------------------------------
__global__ __launch_bounds__(256) void k_focus(unsigned short* __restrict__ qkv,
                                               const float* __restrict__ rsc) {
  const int wave = threadIdx.x >> 6, lane = threadIdx.x & 63;
  const int t = blockIdx.x * 4 + wave;        // token
  const size_t base = (size_t)t * QKVC + lane * 4;

  uint2 qu = *reinterpret_cast<const uint2*>(qkv + base);
  uint2 ku = *reinterpret_cast<const uint2*>(qkv + base + C_);
  const f32x4 rs = *reinterpret_cast<const f32x4*>(rsc + lane * 4);

  float q[4], k[4], q3[4], k3[4];
  q[0] = blo(qu.x); q[1] = bhi(qu.x); q[2] = blo(qu.y); q[3] = bhi(qu.y);
  k[0] = blo(ku.x); k[1] = bhi(ku.x); k[2] = blo(ku.y); k[3] = bhi(ku.y);

  float sq2 = 0.f, sq6 = 0.f, sk2 = 0.f, sk6 = 0.f;
#pragma unroll
  for (int i = 0; i < 4; ++i) {
    q[i] = (fmaxf(q[i], 0.f) + EPS_) * rs[i];
    k[i] = (fmaxf(k[i], 0.f) + EPS_) * rs[i];
    const float q2 = q[i] * q[i], k2 = k[i] * k[i];
    q3[i] = q2 * q[i];
    k3[i] = k2 * k[i];
    sq2 += q2; sk2 += k2;
    sq6 += q3[i] * q3[i];
    sk6 += k3[i] * k3[i];
  }
#pragma unroll
  for (int off = 1; off < 64; off <<= 1) {
    sq2 += __shfl_xor(sq2, off);
    sq6 += __shfl_xor(sq6, off);
    sk2 += __shfl_xor(sk2, off);
    sk6 += __shfl_xor(sk6, off);
  }
  const float fq = sqrtf(sq2 / sq6);
  const float fk = sqrtf(sk2 / sk6);

  uint2 oq, ok;
  oq.x = (unsigned int)f2b(q3[0] * fq) | ((unsigned int)f2b(q3[1] * fq) << 16);
  oq.y = (unsigned int)f2b(q3[2] * fq) | ((unsigned int)f2b(q3[3] * fq) << 16);
  ok.x = (unsigned int)f2b(k3[0] * fk) | ((unsigned int)f2b(k3[1] * fk) << 16);
  ok.y = (unsigned int)f2b(k3[2] * fk) | ((unsigned int)f2b(k3[3] * fk) << 16);
  *reinterpret_cast<uint2*>(qkv + base) = oq;
  *reinterpret_cast<uint2*>(qkv + base + C_) = ok;
}

// ---------------------------------------------------------------------------
// K3: kv partials per (bh, chunk of 256 rows): kvp[c][d], ksump[c]
// (round 17: reg-staged f32 LDS, pad-36, 8 barriers, prefetch-before-compute)
// ---------------------------------------------------------------------------
#define KVP_CHUNKS 16
__global__ __launch_bounds__(256) void k_kv_part(
    const unsigned short* __restrict__ qkv, float* __restrict__ kvp,
    float* __restrict__ ksp) {
  const int bh = blockIdx.x;
  const int chunk = blockIdx.y;
  const int b = bh >> 3, h = bh & 7;
  const int tid = threadIdx.x;
  __shared__ float ksf[64 * 36];   // 9.2 KB, row pitch 36 floats (144 B)
  __shared__ float vsf[64 * 36];

  const int c = tid >> 3;            // 0..31
  const int d0 = (tid & 7) * 4;      // 0,4,..,28
  const int srow = tid >> 2;         // staging row 0..63
  const int sseg = (tid & 3) * 8;    // staging element offset
  const int j0 = chunk * 256;

  float a0 = 0.f, a1 = 0.f, a2 = 0.f, a3 = 0.f, ksum = 0.f;

  uint4 ku, vu;
  {
    const size_t rb = ((size_t)(b * N_ + j0 + srow)) * QKVC + h * HD_ + sseg;
    ku = *reinterpret_cast<const uint4*>(qkv + rb + C_);
    vu = *reinterpret_cast<const uint4*>(qkv + rb + 2 * C_);
  }

  for (int t = 0; t < 4; ++t) {
    {  // convert current regs -> f32 LDS (conversion happens ONCE here)
      f32x4 k0 = {blo(ku.x), bhi(ku.x), blo(ku.y), bhi(ku.y)};
      f32x4 k1 = {blo(ku.z), bhi(ku.z), blo(ku.w), bhi(ku.w)};
      f32x4 v0 = {blo(vu.x), bhi(vu.x), blo(vu.y), bhi(vu.y)};
      f32x4 v1 = {blo(vu.z), bhi(vu.z), blo(vu.w), bhi(vu.w)};
      *reinterpret_cast<f32x4*>(&ksf[srow * 36 + sseg]) = k0;
      *reinterpret_cast<f32x4*>(&ksf[srow * 36 + sseg + 4]) = k1;
      *reinterpret_cast<f32x4*>(&vsf[srow * 36 + sseg]) = v0;
      *reinterpret_cast<f32x4*>(&vsf[srow * 36 + sseg + 4]) = v1;
    }
    __syncthreads();
    if (t < 3) {  // issue next-tile loads; they fly under the compute below
      const size_t rb =
          ((size_t)(b * N_ + j0 + (t + 1) * 64 + srow)) * QKVC + h * HD_ + sseg;
      ku = *reinterpret_cast<const uint4*>(qkv + rb + C_);
      vu = *reinterpret_cast<const uint4*>(qkv + rb + 2 * C_);
    }
#pragma unroll 8
    for (int jj = 0; jj < 64; ++jj) {
      const float kc = ksf[jj * 36 + c];
      const f32x4 vv = *reinterpret_cast<const f32x4*>(&vsf[jj * 36 + d0]);
      a0 += kc * vv[0];
      a1 += kc * vv[1];
      a2 += kc * vv[2];
      a3 += kc * vv[3];
      ksum += kc;  // identical across the 8 threads sharing c; one stores
    }
    __syncthreads();  // LDS free to overwrite next iteration
  }

  float* kvo = kvp + ((size_t)chunk * 128 + bh) * 1024 + c * 32 + d0;
  kvo[0] = a0; kvo[1] = a1; kvo[2] = a2; kvo[3] = a3;
  if ((tid & 7) == 0) ksp[((size_t)chunk * 128 + bh) * 32 + c] = ksum;
}

// ---------------------------------------------------------------------------
// K3b: reduce 16 chunks ONCE -> kvb[128][1024], ksumb[128][32] (round 19).
// ---------------------------------------------------------------------------
__global__ __launch_bounds__(256) void k_kv_reduce(
    const float* __restrict__ kvp, const float* __restrict__ ksp,
    float* __restrict__ kv, float* __restrict__ ksum) {
  const int bh = blockIdx.x;
  for (int p = threadIdx.x; p < 1024; p += 256) {
    float s = 0.f;
#pragma unroll
    for (int ch = 0; ch < KVP_CHUNKS; ++ch)
      s += kvp[((size_t)ch * 128 + bh) * 1024 + p];
    kv[bh * 1024 + p] = s;
  }
  if (threadIdx.x < 32) {
    float s = 0.f;
#pragma unroll
    for (int ch = 0; ch < KVP_CHUNKS; ++ch)
      s += ksp[((size_t)ch * 128 + bh) * 32 + threadIdx.x];
    ksum[bh * 32 + threadIdx.x] = s;
  }
}

// ---------------------------------------------------------------------------
// K4: fused attention MFMA + depthwise conv (round-21 best: R=4, no kv_s
// LDS — B-frags direct from L2-hot kvb; v-halo gloads fly under the MFMA
// phase; conv halo-row register reuse).
// ---------------------------------------------------------------------------
__global__ __launch_bounds__(256) void k_attn_conv_f(
    unsigned short* __restrict__ qkv, const float* __restrict__ kv,
    const float* __restrict__ ksum, const float* __restrict__ dwc_w,
    const float* __restrict__ dwc_b) {
  const int lin = blockIdx.x;               // 0..2047
  const int g2 = (lin & 7) * 256 + (lin >> 3);
  const int bh = g2 >> 4;                   // 0..127
  const int ig = g2 & 15;                   // 4-row group
  const int i0 = ig * 4;
  const int b = bh >> 3, h = bh & 7;
  const int tid = threadIdx.x;
  const int wave = tid >> 6, lane = tid & 63;

  __shared__ float w_s[800];                // [tap][ch]
  __shared__ float b_s[32];
  __shared__ unsigned short v_s[8 * 64 * 32];  // [halo-row][col][ch] 32 KB

  // ---- issue v-halo gloads FIRST; they fly under the attn MFMA phase
#pragma unroll
  for (int rr = 0; rr < 8; ++rr) {
    const int ii = i0 + rr - 2;             // block-uniform condition
    if (ii < 0 || ii >= 64) continue;
    gload_lds16(qkv + ((size_t)(b * N_ + ii * 64 + wave * 16 + (lane >> 2))) * QKVC +
                    2 * C_ + h * HD_ + (lane & 3) * 8,
                &v_s[rr * 2048 + wave * 512]);
  }
  // conv weights into LDS (read only after the mid-kernel barrier)
  for (int p = tid; p < 800; p += 256)
    w_s[p] = dwc_w[(p & 31) * 25 + (p >> 5)];
  if (tid < 32) b_s[tid] = dwc_b[tid];

  // ---- attn phase: wave handles image row i0+wave (64 tokens).
  // B-frags read DIRECTLY from global kvb (L2-hot; no LDS round-trip).
  {
    const int kb = (lane >> 4) * 8;
    const int col = lane & 15;
    const float* kvb_row = kv + bh * 1024;
    const float* ksb = ksum + bh * 32;
    bf16x8 bh0, bh1, bl0, bl1;
    float ks0[8];
#pragma unroll
    for (int t = 0; t < 8; ++t) {
      const float v0 = kvb_row[(kb + t) * 32 + col];
      const float v1 = kvb_row[(kb + t) * 32 + col + 16];
      const unsigned short h0 = f2b(v0), h1 = f2b(v1);
      ((unsigned short*)&bh0)[t] = h0;
      ((unsigned short*)&bh1)[t] = h1;
      ((unsigned short*)&bl0)[t] = f2b(v0 - b2f(h0));
      ((unsigned short*)&bl1)[t] = f2b(v1 - b2f(h1));
      ks0[t] = ksb[kb + t];
    }
    const int r0 = (i0 + wave) * 64;
#pragma unroll
    for (int rt = 0; rt < 4; ++rt) {
      const int row = r0 + rt * 16 + (lane & 15);
      const bf16x8 a = *reinterpret_cast<const bf16x8*>(
          qkv + (size_t)(b * N_ + row) * QKVC + h * HD_ + kb);
      float zp = 0.f;
#pragma unroll
      for (int t = 0; t < 8; ++t)
        zp += b2f(((const unsigned short*)&a)[t]) * ks0[t];
      zp += __shfl_xor(zp, 16);
      zp += __shfl_xor(zp, 32);
      const float z = 1.f / (zp + EPS_);

      f32x4 acc0 = {0.f, 0.f, 0.f, 0.f}, acc1 = {0.f, 0.f, 0.f, 0.f};
      acc0 = __builtin_amdgcn_mfma_f32_16x16x32_bf16(a, bl0, acc0, 0, 0, 0);
      acc1 = __builtin_amdgcn_mfma_f32_16x16x32_bf16(a, bl1, acc1, 0, 0, 0);
      acc0 = __builtin_amdgcn_mfma_f32_16x16x32_bf16(a, bh0, acc0, 0, 0, 0);
      acc1 = __builtin_amdgcn_mfma_f32_16x16x32_bf16(a, bh1, acc1, 0, 0, 0);

#pragma unroll
      for (int r = 0; r < 4; ++r) {
        const int rr = (lane >> 4) * 4 + r;
        const float zr = __shfl(z, rr);
        unsigned short* op =
            qkv + (size_t)(b * N_ + r0 + rt * 16 + rr) * QKVC + h * HD_;
        op[col] = f2b(acc0[r] * zr);
        op[col + 16] = f2b(acc1[r] * zr);
      }
    }
  }
  __syncthreads();  // drains v-halo gloads AND attn q-slot writes (block-local)

  // ---- conv phase: thread = (image col j, channel group); halo-row reuse
  {
    const int j = tid >> 2;
    const int d0 = (tid & 3) * 8;
    float fm[4][8];
#pragma unroll
    for (int r = 0; r < 4; ++r)
#pragma unroll
      for (int dd = 0; dd < 8; ++dd) fm[r][dd] = b_s[d0 + dd];

#pragma unroll
    for (int lr = 0; lr < 8; ++lr) {        // halo row (image row i0+lr-2)
      const int ii = i0 + lr - 2;
      if (ii < 0 || ii >= 64) continue;     // block-uniform
#pragma unroll
      for (int kj = 0; kj < 5; ++kj) {
        const int jj = j + kj - 2;
        if (jj < 0 || jj >= 64) continue;
        const unsigned int* vr = reinterpret_cast<const unsigned int*>(
            &v_s[lr * 2048 + jj * 32 + d0]);
        float vf[8];
#pragma unroll
        for (int p = 0; p < 4; ++p) {       // unpack ONCE per loaded value
          const unsigned int vu = vr[p];
          vf[2 * p + 0] = blo(vu);
          vf[2 * p + 1] = bhi(vu);
        }
#pragma unroll
        for (int r = 0; r < 4; ++r) {       // all output rows this row feeds
          const int kr = lr - r;            // compile-time after unroll
          if (kr < 0 || kr > 4) continue;
          const float* wt = &w_s[(kr * 5 + kj) * 32 + d0];
#pragma unroll
          for (int dd = 0; dd < 8; ++dd) fm[r][dd] += vf[dd] * wt[dd];
        }
      }
    }

#pragma unroll
    for (int r = 0; r < 4; ++r) {
      const int i = i0 + r;
      unsigned int* orow = reinterpret_cast<unsigned int*>(
          qkv + ((size_t)(b * N_ + i * 64 + j)) * QKVC + h * HD_ + d0);
      uint4 cur = *reinterpret_cast<const uint4*>(orow);
      unsigned int o[4] = {cur.x, cur.y, cur.z, cur.w};
#pragma unroll
      for (int p = 0; p < 4; ++p) {
        const unsigned int lo = f2b(blo(o[p]) + fm[r][2 * p + 0]);
        const unsigned int hi = f2b(bhi(o[p]) + fm[r][2 * p + 1]);
        o[p] = lo | (hi << 16);
      }
      *reinterpret_cast<uint4*>(orow) = make_uint4(o[0], o[1], o[2], o[3]);
    }
  }
}

// ---------------------------------------------------------------------------
extern "C" void kernel_launch(void* const* d_in, const int* in_sizes, int n_in,
                              void* d_out, int out_size, void* d_ws,
                              size_t ws_size, hipStream_t stream) {
  (void)in_sizes; (void)n_in; (void)out_size; (void)ws_size;
  const float* x      = (const float*)d_in[0];
  const float* qkv_w  = (const float*)d_in[1];
  const float* qkv_b  = (const float*)d_in[2];
  const float* proj_w = (const float*)d_in[3];
  const float* proj_b = (const float*)d_in[4];
  const float* dwc_w  = (const float*)d_in[5];
  const float* dwc_b  = (const float*)d_in[6];
  const float* scale  = (const float*)d_in[7];
  float* out = (float*)d_out;

  char* w = (char*)d_ws;
  unsigned short* xT   = (unsigned short*)w; w += (size_t)M_ * C_ * 2;     // 33.6MB
  unsigned short* qkvb = (unsigned short*)w; w += (size_t)M_ * QKVC * 2;   // 100.7MB
  // Reserve space for BOTH weight matrices (round-3 NaN was wp aliasing kvp).
  unsigned short* wq   = (unsigned short*)w; w += (size_t)(QKVC + C_) * C_ * 2;
  unsigned short* wp   = wq + (size_t)QKVC * C_;
  float* kvp   = (float*)w;                  w += (size_t)KVP_CHUNKS * 128 * 1024 * 4;
  float* ksp   = (float*)w;                  w += (size_t)KVP_CHUNKS * 128 * 32 * 4;
  float* kvb   = (float*)w;                  w += 128 * 1024 * 4;
  float* ksumb = (float*)w;                  w += 128 * 32 * 4;
  float* rscb  = (float*)w;                  w += 256 * 4;

  k_prep_scale<<<1, 256, 0, stream>>>(scale, rscb);
  k_cast_x<<<dim3(N_ / 32, C_ / 32, B_), 256, 0, stream>>>(x, xT);
  k_cast_w<<<256, 256, 0, stream>>>(qkv_w, proj_w, wq);
  k_gemm<256, 0, 6><<<dim3(512, 6), 256, 0, stream>>>(
      xT, wq, qkv_b, (void*)qkvb);
  k_focus<<<M_ / 4, 256, 0, stream>>>(qkvb, rscb);
  k_kv_part<<<dim3(128, KVP_CHUNKS), 256, 0, stream>>>(qkvb, kvp, ksp);
  k_kv_reduce<<<128, 256, 0, stream>>>(kvp, ksp, kvb, ksumb);
  k_attn_conv_f<<<2048, 256, 0, stream>>>(qkvb, kvb, ksumb, dwc_w, dwc_b);
  k_gemm<768, 1, 2><<<dim3(512, 2), 256, 0, stream>>>(
      qkvb, wp, proj_b, (void*)out);
}